// Round 2
// baseline (3621.144 us; speedup 1.0000x reference)
//
#include <hip/hip_runtime.h>
#include <stdint.h>

#define V_N 25000
#define E_N 50000
#define G_N 1024
#define DIN 74
#define EIN 12
#define NSTEPS 6
#define NS2S 6
#define MPAD 50048   // 391 * 128, padded edge count (zb rows)

typedef unsigned int u32;
typedef unsigned short u16;
typedef __attribute__((ext_vector_type(8))) short bf16x8v;   // 8 bf16 in 4 VGPRs
typedef __attribute__((ext_vector_type(4))) float f32x4v;

typedef __attribute__((address_space(3))) void lds_void;
typedef __attribute__((address_space(1))) void gbl_void;

__device__ __forceinline__ void gload_lds16(const void* g, void* l) {
  __builtin_amdgcn_global_load_lds((gbl_void*)g, (lds_void*)l, 16, 0, 0);
}

__device__ __forceinline__ u16 f2bf(float f) {
  u32 u = __float_as_uint(f);
  u = (u + 0x7fffu + ((u >> 16) & 1u)) >> 16;
  return (u16)u;
}
__device__ __forceinline__ float sigf(float x){ return 1.f/(1.f + expf(-x)); }
__device__ __forceinline__ float splusf(float x){ return fmaxf(x, 0.f) + log1pf(expf(-fabsf(x))); }

// ---------------- one-time prep: weight transposes + W_e2 -> bf16 col-major (WbT[n][k])
__global__ void prep_kernel(const float* gWih, const float* gWhh,
                            const float* lWih0, const float* lWhh0,
                            const float* lWihr, const float* lWhhr,
                            const float* We2,
                            float* gWihT, float* gWhhT,
                            float* lWih0T, float* lWhh0T,
                            float* lWihrT, float* lWhhrT,
                            u16* WbT) {
  int idx = blockIdx.x * 256 + threadIdx.x;
  if (idx < 12288) { int d = idx / 192, r = idx % 192; gWihT[idx] = gWih[r*64 + d]; return; }
  idx -= 12288;
  if (idx < 12288) { int d = idx / 192, r = idx % 192; gWhhT[idx] = gWhh[r*64 + d]; return; }
  idx -= 12288;
  if (idx < 32768) { int k = idx / 256, r = idx % 256; lWih0T[idx] = lWih0[r*128 + k]; return; }
  idx -= 32768;
  if (idx < 16384) { int k = idx / 256, r = idx % 256; lWhh0T[idx] = lWhh0[r*64 + k]; return; }
  idx -= 16384;
  if (idx < 32768) { int l = idx / 16384, rem = idx % 16384; int k = rem / 256, r = rem % 256;
                     lWihrT[idx] = lWihr[l*16384 + r*64 + k]; return; }
  idx -= 32768;
  if (idx < 32768) { int l = idx / 16384, rem = idx % 16384; int k = rem / 256, r = rem % 256;
                     lWhhrT[idx] = lWhhr[l*16384 + r*64 + k]; return; }
  idx -= 32768;
  { int n = idx / 128, k = idx % 128; WbT[idx] = f2bf(We2[k*4096 + n]); }
}

// ---------------- h0 = relu(node_feats @ W_proj + b_proj), wave per node
__global__ void proj_kernel(const float* nf, const float* Wp, const float* bp, float* h) {
  int v = blockIdx.x * 4 + (threadIdx.x >> 6);
  int o = threadIdx.x & 63;
  if (v >= V_N) return;
  float acc = bp[o];
  const float* row = nf + (size_t)v * DIN;
  #pragma unroll 2
  for (int d = 0; d < DIN; ++d) acc += row[d] * Wp[d*64 + o];
  h[(size_t)v*64 + o] = fmaxf(acc, 0.f);
}

// ---------------- z = relu(edge_feats @ W_e1 + b_e1) -> bf16, padded rows get 0
__global__ void edgenet_kernel(const float* ef, const float* W1, const float* b1, u16* zb) {
  int e = blockIdx.x * 2 + (threadIdx.x >> 7);
  int k = threadIdx.x & 127;
  float acc = 0.f;
  if (e < E_N) {
    acc = b1[k];
    const float* row = ef + (size_t)e * EIN;
    #pragma unroll
    for (int i = 0; i < EIN; ++i) acc += row[i] * W1[i*128 + k];
    acc = fmaxf(acc, 0.f);
  }
  zb[(size_t)e*128 + k] = f2bf(acc);
}

// ---------------- fused per-step message kernel:
//   per edge e: m = h[src] (1x64) @ reshape(z_e @ W_e2 + b_e2, 64,64); atomicAdd into agg[dst]
// Block = 128 edges, 512 threads (8 waves, wave w owns edge rows w*16..w*16+15).
// Streams N=4096 in 32 col-tiles of 128; col = d*64+o so each tile covers d0=2*nt, d0+1.
// LDS 16B chunks XOR-swizzled: slot = chunk ^ (row&7); linear gload_lds dest + pre-swizzled src.
__global__ __launch_bounds__(512) void fusedmsg_kernel(const u16* zb, const u16* WbT, const float* be2,
                                                       const float* h, const int* src, const int* dst,
                                                       float* agg) {
  __shared__ __align__(16) u16 As[16384];      // 128 edges x 128 k
  __shared__ __align__(16) u16 Bs[2][16384];   // 128 cols x 128 k, double-buffered
  __shared__ float hS[128][66];                // gathered h[src[e]] rows (+2 pad: kill bank conflict)
  int t = threadIdx.x;
  int e0 = blockIdx.x * 128;

  // gather h rows for this block's edges (coalesced 256B per edge row)
  for (int it = 0; it < 16; ++it) {
    int idx = it * 512 + t;                    // 8192 = 128*64
    int el = idx >> 6, d = idx & 63;
    int e = e0 + el;
    int sv = (e < E_N) ? src[e] : 0;
    hS[el][d] = h[(size_t)sv * 64 + d];
  }

  // stage A (z tile): 2048 16B chunks
  {
    const char* Ag = (const char*)(zb + (size_t)e0 * 128);
    char* Al = (char*)As;
    #pragma unroll
    for (int it = 0; it < 4; ++it) {
      int f = it * 512 + t;
      int r = f >> 4, s = f & 15;
      int gc = s ^ (r & 7);
      gload_lds16(Ag + r*256 + gc*16, Al + (size_t)(f & ~63) * 16);
    }
  }
  // stage B tile 0
  {
    const char* Bg = (const char*)WbT;
    char* Bl = (char*)Bs[0];
    #pragma unroll
    for (int it = 0; it < 4; ++it) {
      int f = it * 512 + t;
      int r = f >> 4, s = f & 15;
      int gc = s ^ (r & 7);
      gload_lds16(Bg + r*256 + gc*16, Bl + (size_t)(f & ~63) * 16);
    }
  }
  __syncthreads();

  int w = t >> 6, lane = t & 63;
  float macc[4][4];                            // [n'][r] : o = n'*16+(lane&15), row = w*16+(lane>>4)*4+r
  #pragma unroll
  for (int np = 0; np < 4; ++np)
    #pragma unroll
    for (int r = 0; r < 4; ++r) macc[np][r] = 0.f;

  for (int nt = 0; nt < 32; ++nt) {
    int buf = nt & 1;
    if (nt < 31) {                             // prefetch next B tile into buf^1
      const char* Bg = (const char*)(WbT + (size_t)(nt + 1) * 128 * 128);
      char* Bl = (char*)Bs[buf ^ 1];
      #pragma unroll
      for (int it = 0; it < 4; ++it) {
        int f = it * 512 + t;
        int r = f >> 4, s = f & 15;
        int gc = s ^ (r & 7);
        gload_lds16(Bg + r*256 + gc*16, Bl + (size_t)(f & ~63) * 16);
      }
    }
    // C tile = z @ W_e2 + b_e2 for cols [nt*128, nt*128+128)
    f32x4v acc[8];
    #pragma unroll
    for (int n = 0; n < 8; ++n) {
      float b = be2[nt*128 + n*16 + (lane & 15)];
      acc[n] = (f32x4v){b, b, b, b};
    }
    const char* Ab = (const char*)As;
    const char* Bb = (const char*)Bs[buf];
    #pragma unroll
    for (int ks = 0; ks < 4; ++ks) {
      int cb = ks * 4 + (lane >> 4);
      int arow = w*16 + (lane & 15);
      bf16x8v af = *(const bf16x8v*)(Ab + arow*256 + ((cb ^ (arow & 7)) << 4));
      #pragma unroll
      for (int n = 0; n < 8; ++n) {
        int brow = n*16 + (lane & 15);
        bf16x8v bf = *(const bf16x8v*)(Bb + brow*256 + ((cb ^ (brow & 7)) << 4));
        acc[n] = __builtin_amdgcn_mfma_f32_16x16x32_bf16(af, bf, acc[n], 0, 0, 0);
      }
    }
    // contract with h: cols n<4 -> d0, n>=4 -> d0+1; o = (n&3)*16+(lane&15)
    int d0 = nt * 2;
    #pragma unroll
    for (int r = 0; r < 4; ++r) {
      int row = w*16 + ((lane >> 4) << 2) + r;
      float h0 = hS[row][d0], h1 = hS[row][d0 + 1];
      #pragma unroll
      for (int np = 0; np < 4; ++np)
        macc[np][r] += h0 * acc[np][r] + h1 * acc[np + 4][r];
    }
    __syncthreads();                           // readers done with Bs[buf] + prefetch drained
  }

  // scatter messages
  #pragma unroll
  for (int r = 0; r < 4; ++r) {
    int row = w*16 + ((lane >> 4) << 2) + r;
    int e = e0 + row;
    if (e < E_N) {
      int dv = dst[e];
      #pragma unroll
      for (int np = 0; np < 4; ++np)
        atomicAdd(&agg[(size_t)dv*64 + np*16 + (lane & 15)], macc[np][r]);
    }
  }
}

// ---------------- GRU: h = GRU(relu(agg + b_conv), h); wave handles 4 nodes, in-place
__global__ void gru_kernel(const float* agg, const float* bconv, const float* WihT, const float* WhhT,
                           const float* bih, const float* bhh, float* h) {
  int wbase = (blockIdx.x * 4 + (threadIdx.x >> 6)) * 4;
  int o = threadIdx.x & 63;
  float xv[4], hv[4];
  #pragma unroll
  for (int n = 0; n < 4; ++n) {
    int v = wbase + n;
    if (v < V_N) { xv[n] = fmaxf(agg[(size_t)v*64 + o] + bconv[o], 0.f); hv[n] = h[(size_t)v*64 + o]; }
    else { xv[n] = 0.f; hv[n] = 0.f; }
  }
  float ar[4] = {0,0,0,0}, az[4] = {0,0,0,0}, an[4] = {0,0,0,0};
  float br[4] = {0,0,0,0}, bz[4] = {0,0,0,0}, bn2[4] = {0,0,0,0};
  #pragma unroll 4
  for (int d = 0; d < 64; ++d) {
    float wr = WihT[d*192 + o], wz = WihT[d*192 + 64 + o], wn = WihT[d*192 + 128 + o];
    float ur = WhhT[d*192 + o], uz = WhhT[d*192 + 64 + o], un = WhhT[d*192 + 128 + o];
    #pragma unroll
    for (int n = 0; n < 4; ++n) {
      float xd = __shfl(xv[n], d);
      float hd = __shfl(hv[n], d);
      ar[n] += xd*wr; az[n] += xd*wz; an[n] += xd*wn;
      br[n] += hd*ur; bz[n] += hd*uz; bn2[n] += hd*un;
    }
  }
  float b_r = bih[o] + bhh[o], b_z = bih[64+o] + bhh[64+o];
  float bin = bih[128+o], bhn = bhh[128+o];
  #pragma unroll
  for (int n = 0; n < 4; ++n) {
    int v = wbase + n;
    if (v >= V_N) continue;
    float r  = sigf(ar[n] + br[n] + b_r);
    float z  = sigf(az[n] + bz[n] + b_z);
    float nn = tanhf(an[n] + bin + r*(bn2[n] + bhn));
    h[(size_t)v*64 + o] = (1.f - z)*nn + z*hv[n];
  }
}

// ---------------- graph segment starts via binary search (node2graph is sorted)
__global__ void gstart_kernel(const int* n2g, int* gstart) {
  int g = blockIdx.x * 256 + threadIdx.x;
  if (g > G_N) return;
  int lo = 0, hi = V_N;
  while (lo < hi) { int mid = (lo + hi) >> 1; if (n2g[mid] < g) lo = mid + 1; else hi = mid; }
  gstart[g] = lo;
}

// ---------------- fused Set2Set: 2 graphs per 256-thread block, all 6 iters in one kernel
__global__ __launch_bounds__(256) void s2s_kernel(const float* h, const int* gstart,
    const float* Wih0T, const float* Whh0T, const float* WihrT, const float* WhhrT,
    const float* bih0, const float* bhh0, const float* bihr, const float* bhhr,
    float* qstar) {
  __shared__ float sq[2][128], sx[2][128];
  __shared__ float shs[2][3][64], scs[2][3][64];
  __shared__ float sg[2][256];
  __shared__ float sred[2][2][66];   // [graph][wave][0..63 acc | 64 max | 65 sum]
  int s = threadIdx.x >> 7;
  int tt = threadIdx.x & 127;
  int g = blockIdx.x * 2 + s;
  int w = tt >> 6, lane = tt & 63;
  int nstart = gstart[g], nend = gstart[g + 1];
  sq[s][tt] = 0.f;
  if (tt < 64) { for (int l = 0; l < 3; ++l) { shs[s][l][tt] = 0.f; scs[s][l][tt] = 0.f; } }
  __syncthreads();
  for (int iter = 0; iter < NS2S; ++iter) {
    sx[s][tt] = sq[s][tt];
    __syncthreads();
    // 3-layer stacked LSTM (seq len 1); thread tt computes gate rows tt and tt+128
    for (int l = 0; l < 3; ++l) {
      const float* TW = (l == 0) ? Wih0T : WihrT + (l-1)*16384;
      const float* TU = (l == 0) ? Whh0T : WhhrT + (l-1)*16384;
      const float* bi = (l == 0) ? bih0 : bihr + (l-1)*256;
      const float* bh = (l == 0) ? bhh0 : bhhr + (l-1)*256;
      int K = (l == 0) ? 128 : 64;
      float g0 = bi[tt] + bh[tt];
      float g1 = bi[tt+128] + bh[tt+128];
      for (int k = 0; k < K; ++k) { float xk = sx[s][k]; g0 += xk*TW[k*256 + tt]; g1 += xk*TW[k*256 + tt + 128]; }
      for (int k = 0; k < 64; ++k) { float hk = shs[s][l][k]; g0 += hk*TU[k*256 + tt]; g1 += hk*TU[k*256 + tt + 128]; }
      sg[s][tt] = g0; sg[s][tt+128] = g1;
      __syncthreads();
      if (tt < 64) {
        float gi = sg[s][tt], gf = sg[s][64+tt], gg = sg[s][128+tt], go = sg[s][192+tt];
        float c = sigf(gf)*scs[s][l][tt] + sigf(gi)*tanhf(gg);
        float hc = sigf(go)*tanhf(c);
        scs[s][l][tt] = c; shs[s][l][tt] = hc; sx[s][tt] = hc;
      }
      __syncthreads();
    }
    // attention: q = sx[0:64]; 2 waves per graph stride nodes; 2-pass softmax
    float q_l = sx[s][lane];
    float lmax = -3.4e38f;
    for (int i = nstart + w; i < nend; i += 2) {
      float hval = h[(size_t)i*64 + lane];
      float v = hval * q_l;
      #pragma unroll
      for (int off = 32; off; off >>= 1) v += __shfl_xor(v, off);
      lmax = fmaxf(lmax, v);
    }
    if (lane == 0) sred[s][w][64] = lmax;
    __syncthreads();
    float gmax = fmaxf(sred[s][0][64], sred[s][1][64]);
    float lsum = 0.f, accv = 0.f;
    for (int i = nstart + w; i < nend; i += 2) {
      float hval = h[(size_t)i*64 + lane];
      float v = hval * q_l;
      #pragma unroll
      for (int off = 32; off; off >>= 1) v += __shfl_xor(v, off);
      float wexp = expf(v - gmax);
      lsum += wexp; accv += wexp * hval;
    }
    sred[s][w][lane] = accv;
    if (lane == 0) sred[s][w][65] = lsum;
    __syncthreads();
    if (tt < 64) {
      float den = sred[s][0][65] + sred[s][1][65];
      float ro = (sred[s][0][tt] + sred[s][1][tt]) / fmaxf(den, 1e-12f);
      sq[s][tt] = sx[s][tt];       // q
      sq[s][64 + tt] = ro;         // readout
    }
    __syncthreads();
  }
  qstar[(size_t)g*128 + tt] = sq[s][tt];
}

// ---------------- head: Linear+ReLU+BN(eval)+Linear + evidential transform; wave per graph
__global__ void head_kernel(const float* qstar, const float* W1, const float* b1,
                            const float* gma, const float* gbe, const float* gme, const float* gva,
                            const float* W2, const float* b2, float* out) {
  __shared__ float hb[4][64];
  int wslot = threadIdx.x >> 6;
  int g = blockIdx.x * 4 + wslot;
  int o = threadIdx.x & 63;
  float acc = b1[o];
  const float* q = qstar + (size_t)g * 128;
  #pragma unroll 4
  for (int k = 0; k < 128; ++k) acc += q[k] * W1[k*64 + o];
  acc = fmaxf(acc, 0.f);
  float hbn = gma[o] * (acc - gme[o]) * rsqrtf(gva[o] + 1e-5f) + gbe[o];
  hb[wslot][o] = hbn;
  __syncthreads();
  if (o < 4) {
    float v = b2[o];
    #pragma unroll 8
    for (int k = 0; k < 64; ++k) v += hb[wslot][k] * W2[k*4 + o];
    float res;
    if (o == 0) res = v;                       // mean (raw)
    else { res = splusf(v) + 1e-6f; if (o == 2) res += 1.f; }   // lam / alpha(+1) / beta
    out[(size_t)g*4 + o] = res;
  }
}

extern "C" void kernel_launch(void* const* d_in, const int* in_sizes, int n_in,
                              void* d_out, int out_size, void* d_ws, size_t ws_size,
                              hipStream_t stream) {
  const float* node_feats = (const float*)d_in[0];
  const float* edge_feats = (const float*)d_in[1];
  const int*   src        = (const int*)d_in[2];
  const int*   dst        = (const int*)d_in[3];
  const int*   n2g        = (const int*)d_in[4];
  const float* W_proj = (const float*)d_in[5];
  const float* b_proj = (const float*)d_in[6];
  const float* W_e1   = (const float*)d_in[7];
  const float* b_e1   = (const float*)d_in[8];
  const float* W_e2   = (const float*)d_in[9];
  const float* b_e2   = (const float*)d_in[10];
  const float* b_conv = (const float*)d_in[11];
  const float* gru_W_ih = (const float*)d_in[12];
  const float* gru_W_hh = (const float*)d_in[13];
  const float* gru_b_ih = (const float*)d_in[14];
  const float* gru_b_hh = (const float*)d_in[15];
  const float* lstm_W_ih0 = (const float*)d_in[16];
  const float* lstm_W_hh0 = (const float*)d_in[17];
  const float* lstm_b_ih0 = (const float*)d_in[18];
  const float* lstm_b_hh0 = (const float*)d_in[19];
  const float* lstm_W_ih_r = (const float*)d_in[20];
  const float* lstm_W_hh_r = (const float*)d_in[21];
  const float* lstm_b_ih_r = (const float*)d_in[22];
  const float* lstm_b_hh_r = (const float*)d_in[23];
  const float* W1 = (const float*)d_in[24];
  const float* b1 = (const float*)d_in[25];
  const float* bn_gamma = (const float*)d_in[26];
  const float* bn_beta  = (const float*)d_in[27];
  const float* bn_mean  = (const float*)d_in[28];
  const float* bn_var   = (const float*)d_in[29];
  const float* W2 = (const float*)d_in[30];
  const float* b2 = (const float*)d_in[31];

  char* ws = (char*)d_ws;
  size_t off = 0;
  auto alloc = [&](size_t n) { size_t c = off; off += (n + 255) & ~(size_t)255; return c; };
  u16*   zb     = (u16*)  (ws + alloc((size_t)MPAD * 128 * 2));   // 12.8 MB
  float* h      = (float*)(ws + alloc((size_t)V_N * 64 * 4));     //  6.4 MB
  float* agg    = (float*)(ws + alloc((size_t)V_N * 64 * 4));     //  6.4 MB
  u16*   WbT    = (u16*)  (ws + alloc((size_t)4096 * 128 * 2));   //  1.0 MB
  float* gWihT  = (float*)(ws + alloc(12288 * 4));
  float* gWhhT  = (float*)(ws + alloc(12288 * 4));
  float* lWih0T = (float*)(ws + alloc(32768 * 4));
  float* lWhh0T = (float*)(ws + alloc(16384 * 4));
  float* lWihrT = (float*)(ws + alloc(32768 * 4));
  float* lWhhrT = (float*)(ws + alloc(32768 * 4));
  int*   gstart = (int*)  (ws + alloc(1025 * 4));
  float* qstar  = (float*)(ws + alloc((size_t)G_N * 128 * 4));
  (void)in_sizes; (void)n_in; (void)out_size; (void)ws_size;

  prep_kernel<<<2592, 256, 0, stream>>>(gru_W_ih, gru_W_hh, lstm_W_ih0, lstm_W_hh0,
                                        lstm_W_ih_r, lstm_W_hh_r, W_e2,
                                        gWihT, gWhhT, lWih0T, lWhh0T, lWihrT, lWhhrT, WbT);
  proj_kernel<<<6250, 256, 0, stream>>>(node_feats, W_proj, b_proj, h);
  edgenet_kernel<<<MPAD / 2, 256, 0, stream>>>(edge_feats, W_e1, b_e1, zb);

  for (int st = 0; st < NSTEPS; ++st) {
    hipMemsetAsync(agg, 0, (size_t)V_N * 64 * 4, stream);
    fusedmsg_kernel<<<MPAD / 128, 512, 0, stream>>>(zb, WbT, b_e2, h, src, dst, agg);
    gru_kernel<<<1563, 256, 0, stream>>>(agg, b_conv, gWihT, gWhhT, gru_b_ih, gru_b_hh, h);
  }

  gstart_kernel<<<5, 256, 0, stream>>>(n2g, gstart);
  s2s_kernel<<<512, 256, 0, stream>>>(h, gstart, lWih0T, lWhh0T, lWihrT, lWhhrT,
                                      lstm_b_ih0, lstm_b_hh0, lstm_b_ih_r, lstm_b_hh_r, qstar);
  head_kernel<<<256, 256, 0, stream>>>(qstar, W1, b1, bn_gamma, bn_beta, bn_mean, bn_var,
                                       W2, b2, (float*)d_out);
}

// Round 3
// 1410.898 us; speedup vs baseline: 2.5666x; 2.5666x over previous
//
#include <hip/hip_runtime.h>
#include <stdint.h>

#define V_N 25000
#define E_N 50000
#define G_N 1024
#define DIN 74
#define EIN 12
#define NSTEPS 6
#define NS2S 6
#define MPAD 50048   // 391 * 128, padded edge count (zb rows)

typedef unsigned int u32;
typedef unsigned short u16;
typedef __attribute__((ext_vector_type(8))) short bf16x8v;   // 8 bf16 in 4 VGPRs
typedef __attribute__((ext_vector_type(4))) float f32x4v;

typedef __attribute__((address_space(3))) void lds_void;
typedef __attribute__((address_space(1))) void gbl_void;

__device__ __forceinline__ void gload_lds16(const void* g, void* l) {
  __builtin_amdgcn_global_load_lds((gbl_void*)g, (lds_void*)l, 16, 0, 0);
}

__device__ __forceinline__ u16 f2bf(float f) {
  u32 u = __float_as_uint(f);
  u = (u + 0x7fffu + ((u >> 16) & 1u)) >> 16;
  return (u16)u;
}
__device__ __forceinline__ u32 pack2bf(float lo, float hi) {
  return (u32)f2bf(lo) | ((u32)f2bf(hi) << 16);
}
__device__ __forceinline__ float bflo(u32 w){ return __uint_as_float(w << 16); }
__device__ __forceinline__ float bfhi(u32 w){ return __uint_as_float(w & 0xffff0000u); }
__device__ __forceinline__ float sigf(float x){ return 1.f/(1.f + expf(-x)); }
__device__ __forceinline__ float splusf(float x){ return fmaxf(x, 0.f) + log1pf(expf(-fabsf(x))); }

// ---------------- one-time prep: GRU transposes + LSTM bf16-pair packs + W_e2 -> bf16 col-major
// LSTM pack layout: TWp[k2*256 + r] = pack(W[r][2k2], W[r][2k2+1])
__global__ void prep_kernel(const float* gWih, const float* gWhh,
                            const float* lWih0, const float* lWhh0,
                            const float* lWihr, const float* lWhhr,
                            const float* We2,
                            float* gWihT, float* gWhhT,
                            u32* TWp0, u32* TUp0, u32* TWpr, u32* TUpr,
                            u16* WbT) {
  int idx = blockIdx.x * 256 + threadIdx.x;
  if (idx < 12288) { int d = idx / 192, r = idx % 192; gWihT[idx] = gWih[r*64 + d]; return; }
  idx -= 12288;
  if (idx < 12288) { int d = idx / 192, r = idx % 192; gWhhT[idx] = gWhh[r*64 + d]; return; }
  idx -= 12288;
  if (idx < 16384) { int k2 = idx >> 8, r = idx & 255;
                     TWp0[idx] = pack2bf(lWih0[r*128 + 2*k2], lWih0[r*128 + 2*k2 + 1]); return; }
  idx -= 16384;
  if (idx < 8192)  { int k2 = idx >> 8, r = idx & 255;
                     TUp0[idx] = pack2bf(lWhh0[r*64 + 2*k2], lWhh0[r*64 + 2*k2 + 1]); return; }
  idx -= 8192;
  if (idx < 16384) { int l = idx >> 13, rem = idx & 8191, k2 = rem >> 8, r = rem & 255;
                     TWpr[idx] = pack2bf(lWihr[l*16384 + r*64 + 2*k2], lWihr[l*16384 + r*64 + 2*k2 + 1]); return; }
  idx -= 16384;
  if (idx < 16384) { int l = idx >> 13, rem = idx & 8191, k2 = rem >> 8, r = rem & 255;
                     TUpr[idx] = pack2bf(lWhhr[l*16384 + r*64 + 2*k2], lWhhr[l*16384 + r*64 + 2*k2 + 1]); return; }
  idx -= 16384;
  { int n = idx / 128, k = idx % 128; WbT[idx] = f2bf(We2[k*4096 + n]); }
}

// ---------------- h0 = relu(node_feats @ W_proj + b_proj), wave per node
__global__ void proj_kernel(const float* nf, const float* Wp, const float* bp, float* h) {
  int v = blockIdx.x * 4 + (threadIdx.x >> 6);
  int o = threadIdx.x & 63;
  if (v >= V_N) return;
  float acc = bp[o];
  const float* row = nf + (size_t)v * DIN;
  #pragma unroll 2
  for (int d = 0; d < DIN; ++d) acc += row[d] * Wp[d*64 + o];
  h[(size_t)v*64 + o] = fmaxf(acc, 0.f);
}

// ---------------- z = relu(edge_feats @ W_e1 + b_e1) -> bf16, padded rows get 0
__global__ void edgenet_kernel(const float* ef, const float* W1, const float* b1, u16* zb) {
  int e = blockIdx.x * 2 + (threadIdx.x >> 7);
  int k = threadIdx.x & 127;
  float acc = 0.f;
  if (e < E_N) {
    acc = b1[k];
    const float* row = ef + (size_t)e * EIN;
    #pragma unroll
    for (int i = 0; i < EIN; ++i) acc += row[i] * W1[i*128 + k];
    acc = fmaxf(acc, 0.f);
  }
  zb[(size_t)e*128 + k] = f2bf(acc);
}

// ---------------- fused per-step message kernel (unchanged from passing round 2)
__global__ __launch_bounds__(512) void fusedmsg_kernel(const u16* zb, const u16* WbT, const float* be2,
                                                       const float* h, const int* src, const int* dst,
                                                       float* agg) {
  __shared__ __align__(16) u16 As[16384];      // 128 edges x 128 k
  __shared__ __align__(16) u16 Bs[2][16384];   // 128 cols x 128 k, double-buffered
  __shared__ float hS[128][66];                // gathered h[src[e]] rows
  int t = threadIdx.x;
  int e0 = blockIdx.x * 128;

  for (int it = 0; it < 16; ++it) {
    int idx = it * 512 + t;
    int el = idx >> 6, d = idx & 63;
    int e = e0 + el;
    int sv = (e < E_N) ? src[e] : 0;
    hS[el][d] = h[(size_t)sv * 64 + d];
  }
  {
    const char* Ag = (const char*)(zb + (size_t)e0 * 128);
    char* Al = (char*)As;
    #pragma unroll
    for (int it = 0; it < 4; ++it) {
      int f = it * 512 + t;
      int r = f >> 4, s = f & 15;
      int gc = s ^ (r & 7);
      gload_lds16(Ag + r*256 + gc*16, Al + (size_t)(f & ~63) * 16);
    }
  }
  {
    const char* Bg = (const char*)WbT;
    char* Bl = (char*)Bs[0];
    #pragma unroll
    for (int it = 0; it < 4; ++it) {
      int f = it * 512 + t;
      int r = f >> 4, s = f & 15;
      int gc = s ^ (r & 7);
      gload_lds16(Bg + r*256 + gc*16, Bl + (size_t)(f & ~63) * 16);
    }
  }
  __syncthreads();

  int w = t >> 6, lane = t & 63;
  float macc[4][4];
  #pragma unroll
  for (int np = 0; np < 4; ++np)
    #pragma unroll
    for (int r = 0; r < 4; ++r) macc[np][r] = 0.f;

  for (int nt = 0; nt < 32; ++nt) {
    int buf = nt & 1;
    if (nt < 31) {
      const char* Bg = (const char*)(WbT + (size_t)(nt + 1) * 128 * 128);
      char* Bl = (char*)Bs[buf ^ 1];
      #pragma unroll
      for (int it = 0; it < 4; ++it) {
        int f = it * 512 + t;
        int r = f >> 4, s = f & 15;
        int gc = s ^ (r & 7);
        gload_lds16(Bg + r*256 + gc*16, Bl + (size_t)(f & ~63) * 16);
      }
    }
    f32x4v acc[8];
    #pragma unroll
    for (int n = 0; n < 8; ++n) {
      float b = be2[nt*128 + n*16 + (lane & 15)];
      acc[n] = (f32x4v){b, b, b, b};
    }
    const char* Ab = (const char*)As;
    const char* Bb = (const char*)Bs[buf];
    #pragma unroll
    for (int ks = 0; ks < 4; ++ks) {
      int cb = ks * 4 + (lane >> 4);
      int arow = w*16 + (lane & 15);
      bf16x8v af = *(const bf16x8v*)(Ab + arow*256 + ((cb ^ (arow & 7)) << 4));
      #pragma unroll
      for (int n = 0; n < 8; ++n) {
        int brow = n*16 + (lane & 15);
        bf16x8v bf = *(const bf16x8v*)(Bb + brow*256 + ((cb ^ (brow & 7)) << 4));
        acc[n] = __builtin_amdgcn_mfma_f32_16x16x32_bf16(af, bf, acc[n], 0, 0, 0);
      }
    }
    int d0 = nt * 2;
    #pragma unroll
    for (int r = 0; r < 4; ++r) {
      int row = w*16 + ((lane >> 4) << 2) + r;
      float h0 = hS[row][d0], h1 = hS[row][d0 + 1];
      #pragma unroll
      for (int np = 0; np < 4; ++np)
        macc[np][r] += h0 * acc[np][r] + h1 * acc[np + 4][r];
    }
    __syncthreads();
  }

  #pragma unroll
  for (int r = 0; r < 4; ++r) {
    int row = w*16 + ((lane >> 4) << 2) + r;
    int e = e0 + row;
    if (e < E_N) {
      int dv = dst[e];
      #pragma unroll
      for (int np = 0; np < 4; ++np)
        atomicAdd(&agg[(size_t)dv*64 + np*16 + (lane & 15)], macc[np][r]);
    }
  }
}

// ---------------- GRU: h = GRU(relu(agg + b_conv), h); wave handles 4 nodes, in-place
__global__ void gru_kernel(const float* agg, const float* bconv, const float* WihT, const float* WhhT,
                           const float* bih, const float* bhh, float* h) {
  int wbase = (blockIdx.x * 4 + (threadIdx.x >> 6)) * 4;
  int o = threadIdx.x & 63;
  float xv[4], hv[4];
  #pragma unroll
  for (int n = 0; n < 4; ++n) {
    int v = wbase + n;
    if (v < V_N) { xv[n] = fmaxf(agg[(size_t)v*64 + o] + bconv[o], 0.f); hv[n] = h[(size_t)v*64 + o]; }
    else { xv[n] = 0.f; hv[n] = 0.f; }
  }
  float ar[4] = {0,0,0,0}, az[4] = {0,0,0,0}, an[4] = {0,0,0,0};
  float br[4] = {0,0,0,0}, bz[4] = {0,0,0,0}, bn2[4] = {0,0,0,0};
  #pragma unroll 4
  for (int d = 0; d < 64; ++d) {
    float wr = WihT[d*192 + o], wz = WihT[d*192 + 64 + o], wn = WihT[d*192 + 128 + o];
    float ur = WhhT[d*192 + o], uz = WhhT[d*192 + 64 + o], un = WhhT[d*192 + 128 + o];
    #pragma unroll
    for (int n = 0; n < 4; ++n) {
      float xd = __shfl(xv[n], d);
      float hd = __shfl(hv[n], d);
      ar[n] += xd*wr; az[n] += xd*wz; an[n] += xd*wn;
      br[n] += hd*ur; bz[n] += hd*uz; bn2[n] += hd*un;
    }
  }
  float b_r = bih[o] + bhh[o], b_z = bih[64+o] + bhh[64+o];
  float bin = bih[128+o], bhn = bhh[128+o];
  #pragma unroll
  for (int n = 0; n < 4; ++n) {
    int v = wbase + n;
    if (v >= V_N) continue;
    float r  = sigf(ar[n] + br[n] + b_r);
    float z  = sigf(az[n] + bz[n] + b_z);
    float nn = tanhf(an[n] + bin + r*(bn2[n] + bhn));
    h[(size_t)v*64 + o] = (1.f - z)*nn + z*hv[n];
  }
}

// ---------------- graph segment starts via binary search (node2graph is sorted)
__global__ void gstart_kernel(const int* n2g, int* gstart) {
  int g = blockIdx.x * 256 + threadIdx.x;
  if (g > G_N) return;
  int lo = 0, hi = V_N;
  while (lo < hi) { int mid = (lo + hi) >> 1; if (n2g[mid] < g) lo = mid + 1; else hi = mid; }
  gstart[g] = lo;
}

// ---------------- fused Set2Set v2: 4 graphs per 256-thread block, 256 blocks.
// LSTM: thread tt computes gate row tt for all 4 graphs (4 independent FMA chains).
// Weights are bf16-pairs packed in u32 (prep); x/h read as wave-uniform float4 LDS broadcasts.
// Attention: 1 wave per graph, ILP-2 over nodes, no cross-wave reduction.
__global__ __launch_bounds__(256, 4) void s2s_kernel(const float* h, const int* gstart,
    const u32* TWp0, const u32* TUp0, const u32* TWpr, const u32* TUpr,
    const float* bih0, const float* bhh0, const float* bihr, const float* bhhr,
    float* qstar) {
  __shared__ float sq[4][128];
  __shared__ float sx[4][128];
  __shared__ float shs[4][3][64], scs[4][3][64];
  __shared__ float sg[4][256];
  int tt = threadIdx.x;
  int g0blk = blockIdx.x * 4;

  for (int i = tt; i < 512; i += 256) ((float*)sq)[i] = 0.f;
  for (int i = tt; i < 768; i += 256) { ((float*)shs)[i] = 0.f; ((float*)scs)[i] = 0.f; }
  __syncthreads();

  for (int iter = 0; iter < NS2S; ++iter) {
    for (int i = tt; i < 512; i += 256) ((float*)sx)[i] = ((float*)sq)[i];
    __syncthreads();

    for (int l = 0; l < 3; ++l) {
      const u32* TW = (l == 0) ? TWp0 : TWpr + (size_t)(l-1) * 8192;
      const u32* TU = (l == 0) ? TUp0 : TUpr + (size_t)(l-1) * 8192;
      const float* bi = (l == 0) ? bih0 : bihr + (l-1)*256;
      const float* bh = (l == 0) ? bhh0 : bhhr + (l-1)*256;
      float bsum = bi[tt] + bh[tt];
      float acc[4] = {bsum, bsum, bsum, bsum};
      if (l == 0) {
        #pragma unroll 8
        for (int k4 = 0; k4 < 32; ++k4) {
          u32 wa = TW[(2*k4)*256 + tt];
          u32 wb = TW[(2*k4+1)*256 + tt];
          float w0 = bflo(wa), w1 = bfhi(wa), w2 = bflo(wb), w3 = bfhi(wb);
          #pragma unroll
          for (int gi = 0; gi < 4; ++gi) {
            const float4 xv = *(const float4*)&sx[gi][4*k4];
            acc[gi] += xv.x*w0 + xv.y*w1 + xv.z*w2 + xv.w*w3;
          }
        }
      } else {
        #pragma unroll 8
        for (int k4 = 0; k4 < 16; ++k4) {
          u32 wa = TW[(2*k4)*256 + tt];
          u32 wb = TW[(2*k4+1)*256 + tt];
          float w0 = bflo(wa), w1 = bfhi(wa), w2 = bflo(wb), w3 = bfhi(wb);
          #pragma unroll
          for (int gi = 0; gi < 4; ++gi) {
            const float4 xv = *(const float4*)&sx[gi][4*k4];
            acc[gi] += xv.x*w0 + xv.y*w1 + xv.z*w2 + xv.w*w3;
          }
        }
      }
      #pragma unroll 8
      for (int k4 = 0; k4 < 16; ++k4) {
        u32 wa = TU[(2*k4)*256 + tt];
        u32 wb = TU[(2*k4+1)*256 + tt];
        float w0 = bflo(wa), w1 = bfhi(wa), w2 = bflo(wb), w3 = bfhi(wb);
        #pragma unroll
        for (int gi = 0; gi < 4; ++gi) {
          const float4 hv = *(const float4*)&shs[gi][l][4*k4];
          acc[gi] += hv.x*w0 + hv.y*w1 + hv.z*w2 + hv.w*w3;
        }
      }
      #pragma unroll
      for (int gi = 0; gi < 4; ++gi) sg[gi][tt] = acc[gi];
      __syncthreads();
      {
        int gq = tt >> 6, r = tt & 63;
        float gv_i = sg[gq][r], gv_f = sg[gq][64+r], gv_g = sg[gq][128+r], gv_o = sg[gq][192+r];
        float c = sigf(gv_f)*scs[gq][l][r] + sigf(gv_i)*tanhf(gv_g);
        float hc = sigf(gv_o)*tanhf(c);
        scs[gq][l][r] = c; shs[gq][l][r] = hc; sx[gq][r] = hc;
      }
      __syncthreads();
    }

    // attention: wave w owns graph g0blk+w; q = sx[w][0:64]
    {
      int w = tt >> 6, lane = tt & 63;
      int nstart = gstart[g0blk + w], nend = gstart[g0blk + w + 1];
      float q_l = sx[w][lane];
      float lmax = -3.4e38f;
      int i = nstart;
      for (; i + 1 < nend; i += 2) {
        float h0 = h[(size_t)i*64 + lane];
        float h1 = h[(size_t)(i+1)*64 + lane];
        float v0 = h0 * q_l, v1 = h1 * q_l;
        #pragma unroll
        for (int off = 32; off; off >>= 1) { v0 += __shfl_xor(v0, off); v1 += __shfl_xor(v1, off); }
        lmax = fmaxf(lmax, fmaxf(v0, v1));
      }
      if (i < nend) {
        float h0 = h[(size_t)i*64 + lane];
        float v0 = h0 * q_l;
        #pragma unroll
        for (int off = 32; off; off >>= 1) v0 += __shfl_xor(v0, off);
        lmax = fmaxf(lmax, v0);
      }
      float lsum = 0.f, accv = 0.f;
      i = nstart;
      for (; i + 1 < nend; i += 2) {
        float h0 = h[(size_t)i*64 + lane];
        float h1 = h[(size_t)(i+1)*64 + lane];
        float v0 = h0 * q_l, v1 = h1 * q_l;
        #pragma unroll
        for (int off = 32; off; off >>= 1) { v0 += __shfl_xor(v0, off); v1 += __shfl_xor(v1, off); }
        float e0 = expf(v0 - lmax), e1 = expf(v1 - lmax);
        lsum += e0 + e1; accv += e0*h0 + e1*h1;
      }
      if (i < nend) {
        float h0 = h[(size_t)i*64 + lane];
        float v0 = h0 * q_l;
        #pragma unroll
        for (int off = 32; off; off >>= 1) v0 += __shfl_xor(v0, off);
        float e0 = expf(v0 - lmax);
        lsum += e0; accv += e0*h0;
      }
      sq[w][lane] = sx[w][lane];
      sq[w][64 + lane] = accv / fmaxf(lsum, 1e-12f);
    }
    __syncthreads();
  }

  for (int i = tt; i < 512; i += 256) qstar[(size_t)g0blk * 128 + i] = ((float*)sq)[i];
}

// ---------------- head: Linear+ReLU+BN(eval)+Linear + evidential transform; wave per graph
__global__ void head_kernel(const float* qstar, const float* W1, const float* b1,
                            const float* gma, const float* gbe, const float* gme, const float* gva,
                            const float* W2, const float* b2, float* out) {
  __shared__ float hb[4][64];
  int wslot = threadIdx.x >> 6;
  int g = blockIdx.x * 4 + wslot;
  int o = threadIdx.x & 63;
  float acc = b1[o];
  const float* q = qstar + (size_t)g * 128;
  #pragma unroll 4
  for (int k = 0; k < 128; ++k) acc += q[k] * W1[k*64 + o];
  acc = fmaxf(acc, 0.f);
  float hbn = gma[o] * (acc - gme[o]) * rsqrtf(gva[o] + 1e-5f) + gbe[o];
  hb[wslot][o] = hbn;
  __syncthreads();
  if (o < 4) {
    float v = b2[o];
    #pragma unroll 8
    for (int k = 0; k < 64; ++k) v += hb[wslot][k] * W2[k*4 + o];
    float res;
    if (o == 0) res = v;
    else { res = splusf(v) + 1e-6f; if (o == 2) res += 1.f; }
    out[(size_t)g*4 + o] = res;
  }
}

extern "C" void kernel_launch(void* const* d_in, const int* in_sizes, int n_in,
                              void* d_out, int out_size, void* d_ws, size_t ws_size,
                              hipStream_t stream) {
  const float* node_feats = (const float*)d_in[0];
  const float* edge_feats = (const float*)d_in[1];
  const int*   src        = (const int*)d_in[2];
  const int*   dst        = (const int*)d_in[3];
  const int*   n2g        = (const int*)d_in[4];
  const float* W_proj = (const float*)d_in[5];
  const float* b_proj = (const float*)d_in[6];
  const float* W_e1   = (const float*)d_in[7];
  const float* b_e1   = (const float*)d_in[8];
  const float* W_e2   = (const float*)d_in[9];
  const float* b_e2   = (const float*)d_in[10];
  const float* b_conv = (const float*)d_in[11];
  const float* gru_W_ih = (const float*)d_in[12];
  const float* gru_W_hh = (const float*)d_in[13];
  const float* gru_b_ih = (const float*)d_in[14];
  const float* gru_b_hh = (const float*)d_in[15];
  const float* lstm_W_ih0 = (const float*)d_in[16];
  const float* lstm_W_hh0 = (const float*)d_in[17];
  const float* lstm_b_ih0 = (const float*)d_in[18];
  const float* lstm_b_hh0 = (const float*)d_in[19];
  const float* lstm_W_ih_r = (const float*)d_in[20];
  const float* lstm_W_hh_r = (const float*)d_in[21];
  const float* lstm_b_ih_r = (const float*)d_in[22];
  const float* lstm_b_hh_r = (const float*)d_in[23];
  const float* W1 = (const float*)d_in[24];
  const float* b1 = (const float*)d_in[25];
  const float* bn_gamma = (const float*)d_in[26];
  const float* bn_beta  = (const float*)d_in[27];
  const float* bn_mean  = (const float*)d_in[28];
  const float* bn_var   = (const float*)d_in[29];
  const float* W2 = (const float*)d_in[30];
  const float* b2 = (const float*)d_in[31];

  char* ws = (char*)d_ws;
  size_t off = 0;
  auto alloc = [&](size_t n) { size_t c = off; off += (n + 255) & ~(size_t)255; return c; };
  u16*   zb     = (u16*)  (ws + alloc((size_t)MPAD * 128 * 2));   // 12.8 MB
  float* h      = (float*)(ws + alloc((size_t)V_N * 64 * 4));     //  6.4 MB
  float* agg    = (float*)(ws + alloc((size_t)V_N * 64 * 4));     //  6.4 MB
  u16*   WbT    = (u16*)  (ws + alloc((size_t)4096 * 128 * 2));   //  1.0 MB
  float* gWihT  = (float*)(ws + alloc(12288 * 4));
  float* gWhhT  = (float*)(ws + alloc(12288 * 4));
  u32*   TWp0   = (u32*)  (ws + alloc(16384 * 4));
  u32*   TUp0   = (u32*)  (ws + alloc(8192 * 4));
  u32*   TWpr   = (u32*)  (ws + alloc(16384 * 4));
  u32*   TUpr   = (u32*)  (ws + alloc(16384 * 4));
  int*   gstart = (int*)  (ws + alloc(1025 * 4));
  float* qstar  = (float*)(ws + alloc((size_t)G_N * 128 * 4));
  (void)in_sizes; (void)n_in; (void)out_size; (void)ws_size;

  prep_kernel<<<2368, 256, 0, stream>>>(gru_W_ih, gru_W_hh, lstm_W_ih0, lstm_W_hh0,
                                        lstm_W_ih_r, lstm_W_hh_r, W_e2,
                                        gWihT, gWhhT, TWp0, TUp0, TWpr, TUpr, WbT);
  proj_kernel<<<6250, 256, 0, stream>>>(node_feats, W_proj, b_proj, h);
  edgenet_kernel<<<MPAD / 2, 256, 0, stream>>>(edge_feats, W_e1, b_e1, zb);

  for (int st = 0; st < NSTEPS; ++st) {
    hipMemsetAsync(agg, 0, (size_t)V_N * 64 * 4, stream);
    fusedmsg_kernel<<<MPAD / 128, 512, 0, stream>>>(zb, WbT, b_e2, h, src, dst, agg);
    gru_kernel<<<1563, 256, 0, stream>>>(agg, b_conv, gWihT, gWhhT, gru_b_ih, gru_b_hh, h);
  }

  gstart_kernel<<<5, 256, 0, stream>>>(n2g, gstart);
  s2s_kernel<<<256, 256, 0, stream>>>(h, gstart, TWp0, TUp0, TWpr, TUpr,
                                      lstm_b_ih0, lstm_b_hh0, lstm_b_ih_r, lstm_b_hh_r, qstar);
  head_kernel<<<256, 256, 0, stream>>>(qstar, W1, b1, bn_gamma, bn_beta, bn_mean, bn_var,
                                       W2, b2, (float*)d_out);
}

// Round 4
// 1227.163 us; speedup vs baseline: 2.9508x; 1.1497x over previous
//
#include <hip/hip_runtime.h>
#include <stdint.h>

#define V_N 25000
#define E_N 50000
#define G_N 1024
#define DIN 74
#define EIN 12
#define NSTEPS 6
#define NS2S 6
#define MPAD 50048   // 391 * 128, padded edge count (zb rows)

typedef unsigned int u32;
typedef unsigned short u16;
typedef __attribute__((ext_vector_type(8))) short bf16x8v;   // 8 bf16 in 4 VGPRs
typedef __attribute__((ext_vector_type(4))) float f32x4v;

typedef __attribute__((address_space(3))) void lds_void;
typedef __attribute__((address_space(1))) void gbl_void;

__device__ __forceinline__ void gload_lds16(const void* g, void* l) {
  __builtin_amdgcn_global_load_lds((gbl_void*)g, (lds_void*)l, 16, 0, 0);
}

__device__ __forceinline__ u16 f2bf(float f) {
  u32 u = __float_as_uint(f);
  u = (u + 0x7fffu + ((u >> 16) & 1u)) >> 16;
  return (u16)u;
}
__device__ __forceinline__ u32 pack2bf(float lo, float hi) {
  return (u32)f2bf(lo) | ((u32)f2bf(hi) << 16);
}
__device__ __forceinline__ float bflo(u32 w){ return __uint_as_float(w << 16); }
__device__ __forceinline__ float bfhi(u32 w){ return __uint_as_float(w & 0xffff0000u); }
__device__ __forceinline__ float sigf(float x){ return 1.f/(1.f + expf(-x)); }
__device__ __forceinline__ float splusf(float x){ return fmaxf(x, 0.f) + log1pf(expf(-fabsf(x))); }

// ---------------- one-time prep: GRU transposes + LSTM bf16-quad packs + W_e2 -> bf16 col-major
// LSTM quad layout: entry q = k8*256 + tt holds uint4; u32 j of it packs W[tt][k8*8+2j], W[tt][k8*8+2j+1]
__global__ void prep_kernel(const float* gWih, const float* gWhh,
                            const float* lWih0, const float* lWhh0,
                            const float* lWihr, const float* lWhhr,
                            const float* We2,
                            float* gWihT, float* gWhhT,
                            u32* TW40, u32* TU40, u32* TW4r, u32* TU4r,
                            u16* WbT) {
  int idx = blockIdx.x * 256 + threadIdx.x;
  if (idx < 12288) { int d = idx / 192, r = idx % 192; gWihT[idx] = gWih[r*64 + d]; return; }
  idx -= 12288;
  if (idx < 12288) { int d = idx / 192, r = idx % 192; gWhhT[idx] = gWhh[r*64 + d]; return; }
  idx -= 12288;
  if (idx < 16384) { int q = idx >> 2, j = idx & 3; int k8 = q >> 8, r = q & 255;
                     TW40[idx] = pack2bf(lWih0[r*128 + k8*8 + 2*j], lWih0[r*128 + k8*8 + 2*j + 1]); return; }
  idx -= 16384;
  if (idx < 8192)  { int q = idx >> 2, j = idx & 3; int k8 = q >> 8, r = q & 255;
                     TU40[idx] = pack2bf(lWhh0[r*64 + k8*8 + 2*j], lWhh0[r*64 + k8*8 + 2*j + 1]); return; }
  idx -= 8192;
  if (idx < 16384) { int l = idx >> 13, rem = idx & 8191; int q = rem >> 2, j = rem & 3;
                     int k8 = q >> 8, r = q & 255;
                     TW4r[idx] = pack2bf(lWihr[l*16384 + r*64 + k8*8 + 2*j],
                                         lWihr[l*16384 + r*64 + k8*8 + 2*j + 1]); return; }
  idx -= 16384;
  if (idx < 16384) { int l = idx >> 13, rem = idx & 8191; int q = rem >> 2, j = rem & 3;
                     int k8 = q >> 8, r = q & 255;
                     TU4r[idx] = pack2bf(lWhhr[l*16384 + r*64 + k8*8 + 2*j],
                                         lWhhr[l*16384 + r*64 + k8*8 + 2*j + 1]); return; }
  idx -= 16384;
  { int n = idx / 128, k = idx % 128; WbT[idx] = f2bf(We2[k*4096 + n]); }
}

// ---------------- h0 = relu(node_feats @ W_proj + b_proj), wave per node
__global__ void proj_kernel(const float* nf, const float* Wp, const float* bp, float* h) {
  int v = blockIdx.x * 4 + (threadIdx.x >> 6);
  int o = threadIdx.x & 63;
  if (v >= V_N) return;
  float acc = bp[o];
  const float* row = nf + (size_t)v * DIN;
  #pragma unroll 2
  for (int d = 0; d < DIN; ++d) acc += row[d] * Wp[d*64 + o];
  h[(size_t)v*64 + o] = fmaxf(acc, 0.f);
}

// ---------------- z = relu(edge_feats @ W_e1 + b_e1) -> bf16, padded rows get 0
__global__ void edgenet_kernel(const float* ef, const float* W1, const float* b1, u16* zb) {
  int e = blockIdx.x * 2 + (threadIdx.x >> 7);
  int k = threadIdx.x & 127;
  float acc = 0.f;
  if (e < E_N) {
    acc = b1[k];
    const float* row = ef + (size_t)e * EIN;
    #pragma unroll
    for (int i = 0; i < EIN; ++i) acc += row[i] * W1[i*128 + k];
    acc = fmaxf(acc, 0.f);
  }
  zb[(size_t)e*128 + k] = f2bf(acc);
}

// ---------------- fused per-step message kernel v2:
// Block = 128 edges, 512 threads = 8 waves tiled 4 row-groups x 2 col-groups
// (wave = 32 edge-rows x 64 cols). Each wave's 64-col half maps to ONE d-parity
// (d0 = 2*nt + wc), o = ni*16+(lane&15). Col-half partials merged in LDS -> half atomics.
__global__ __launch_bounds__(512) void fusedmsg_kernel(const u16* zb, const u16* WbT, const float* be2,
                                                       const float* h, const int* src, const int* dst,
                                                       float* agg) {
  __shared__ __align__(16) u16 As[16384];      // 128 edges x 128 k
  __shared__ __align__(16) u16 Bs[2][16384];   // 128 cols x 128 k, double-buffered
  __shared__ float hS[128][66];                // gathered h[src[e]] rows (+2 pad)
  int t = threadIdx.x;
  int e0 = blockIdx.x * 128;

  for (int it = 0; it < 16; ++it) {
    int idx = it * 512 + t;
    int el = idx >> 6, d = idx & 63;
    int e = e0 + el;
    int sv = (e < E_N) ? src[e] : 0;
    hS[el][d] = h[(size_t)sv * 64 + d];
  }
  {
    const char* Ag = (const char*)(zb + (size_t)e0 * 128);
    char* Al = (char*)As;
    #pragma unroll
    for (int it = 0; it < 4; ++it) {
      int f = it * 512 + t;
      int r = f >> 4, s = f & 15;
      int gc = s ^ (r & 7);
      gload_lds16(Ag + r*256 + gc*16, Al + (size_t)(f & ~63) * 16);
    }
  }
  {
    const char* Bg = (const char*)WbT;
    char* Bl = (char*)Bs[0];
    #pragma unroll
    for (int it = 0; it < 4; ++it) {
      int f = it * 512 + t;
      int r = f >> 4, s = f & 15;
      int gc = s ^ (r & 7);
      gload_lds16(Bg + r*256 + gc*16, Bl + (size_t)(f & ~63) * 16);
    }
  }
  __syncthreads();

  int w = t >> 6, lane = t & 63;
  int wr = w >> 1, wc = w & 1;                 // 4 row-groups x 2 col-groups
  float macc[2][4][4];                         // [mi][ni][r]
  #pragma unroll
  for (int mi = 0; mi < 2; ++mi)
    #pragma unroll
    for (int ni = 0; ni < 4; ++ni)
      #pragma unroll
      for (int r = 0; r < 4; ++r) macc[mi][ni][r] = 0.f;

  for (int nt = 0; nt < 32; ++nt) {
    int buf = nt & 1;
    if (nt < 31) {
      const char* Bg = (const char*)(WbT + (size_t)(nt + 1) * 128 * 128);
      char* Bl = (char*)Bs[buf ^ 1];
      #pragma unroll
      for (int it = 0; it < 4; ++it) {
        int f = it * 512 + t;
        int r = f >> 4, s = f & 15;
        int gc = s ^ (r & 7);
        gload_lds16(Bg + r*256 + gc*16, Bl + (size_t)(f & ~63) * 16);
      }
    }
    // C sub-tile = z @ W_e2 + b_e2, rows [wr*32, +32), cols [wc*64, +64) of 128-col tile nt
    f32x4v acc[2][4];
    #pragma unroll
    for (int ni = 0; ni < 4; ++ni) {
      float b = be2[nt*128 + wc*64 + ni*16 + (lane & 15)];
      #pragma unroll
      for (int mi = 0; mi < 2; ++mi) acc[mi][ni] = (f32x4v){b, b, b, b};
    }
    const char* Ab = (const char*)As;
    const char* Bb = (const char*)Bs[buf];
    #pragma unroll
    for (int ks = 0; ks < 4; ++ks) {
      int cb = ks * 4 + (lane >> 4);
      bf16x8v af[2], bf[4];
      #pragma unroll
      for (int mi = 0; mi < 2; ++mi) {
        int arow = wr*32 + mi*16 + (lane & 15);
        af[mi] = *(const bf16x8v*)(Ab + arow*256 + ((cb ^ (arow & 7)) << 4));
      }
      #pragma unroll
      for (int ni = 0; ni < 4; ++ni) {
        int brow = wc*64 + ni*16 + (lane & 15);
        bf[ni] = *(const bf16x8v*)(Bb + brow*256 + ((cb ^ (brow & 7)) << 4));
      }
      #pragma unroll
      for (int mi = 0; mi < 2; ++mi)
        #pragma unroll
        for (int ni = 0; ni < 4; ++ni)
          acc[mi][ni] = __builtin_amdgcn_mfma_f32_16x16x32_bf16(af[mi], bf[ni], acc[mi][ni], 0, 0, 0);
    }
    // contract with h at d0 = 2*nt + wc
    int d0 = 2*nt + wc;
    #pragma unroll
    for (int mi = 0; mi < 2; ++mi)
      #pragma unroll
      for (int r = 0; r < 4; ++r) {
        int row = wr*32 + mi*16 + ((lane >> 4) << 2) + r;
        float hv = hS[row][d0];
        #pragma unroll
        for (int ni = 0; ni < 4; ++ni)
          macc[mi][ni][r] += hv * acc[mi][ni][r];
      }
    __syncthreads();
  }

  // merge col-half partials (wc=1 -> wc=0) in LDS, then single scatter
  float* red = (float*)Bs;                     // 32 KB needed, 64 KB available
  __syncthreads();
  if (wc == 1) {
    #pragma unroll
    for (int mi = 0; mi < 2; ++mi)
      #pragma unroll
      for (int ni = 0; ni < 4; ++ni)
        #pragma unroll
        for (int r = 0; r < 4; ++r)
          red[((wr*64 + lane)*32) + (mi*4 + ni)*4 + r] = macc[mi][ni][r];
  }
  __syncthreads();
  if (wc == 0) {
    #pragma unroll
    for (int mi = 0; mi < 2; ++mi)
      #pragma unroll
      for (int r = 0; r < 4; ++r) {
        int row = wr*32 + mi*16 + ((lane >> 4) << 2) + r;
        int e = e0 + row;
        if (e < E_N) {
          int dv = dst[e];
          #pragma unroll
          for (int ni = 0; ni < 4; ++ni) {
            float val = macc[mi][ni][r] + red[((wr*64 + lane)*32) + (mi*4 + ni)*4 + r];
            atomicAdd(&agg[(size_t)dv*64 + ni*16 + (lane & 15)], val);
          }
        }
      }
  }
}

// ---------------- GRU: h = GRU(relu(agg + b_conv), h); wave handles 4 nodes; zeroes agg after read
__global__ void gru_kernel(const float* aggc, const float* bconv, const float* WihT, const float* WhhT,
                           const float* bih, const float* bhh, float* h, float* aggz) {
  int wbase = (blockIdx.x * 4 + (threadIdx.x >> 6)) * 4;
  int o = threadIdx.x & 63;
  float xv[4], hv[4];
  #pragma unroll
  for (int n = 0; n < 4; ++n) {
    int v = wbase + n;
    if (v < V_N) { xv[n] = fmaxf(aggc[(size_t)v*64 + o] + bconv[o], 0.f); hv[n] = h[(size_t)v*64 + o]; }
    else { xv[n] = 0.f; hv[n] = 0.f; }
  }
  float ar[4] = {0,0,0,0}, az[4] = {0,0,0,0}, an[4] = {0,0,0,0};
  float br[4] = {0,0,0,0}, bz[4] = {0,0,0,0}, bn2[4] = {0,0,0,0};
  #pragma unroll 4
  for (int d = 0; d < 64; ++d) {
    float wr = WihT[d*192 + o], wz = WihT[d*192 + 64 + o], wn = WihT[d*192 + 128 + o];
    float ur = WhhT[d*192 + o], uz = WhhT[d*192 + 64 + o], un = WhhT[d*192 + 128 + o];
    #pragma unroll
    for (int n = 0; n < 4; ++n) {
      float xd = __shfl(xv[n], d);
      float hd = __shfl(hv[n], d);
      ar[n] += xd*wr; az[n] += xd*wz; an[n] += xd*wn;
      br[n] += hd*ur; bz[n] += hd*uz; bn2[n] += hd*un;
    }
  }
  float b_r = bih[o] + bhh[o], b_z = bih[64+o] + bhh[64+o];
  float bin = bih[128+o], bhn = bhh[128+o];
  #pragma unroll
  for (int n = 0; n < 4; ++n) {
    int v = wbase + n;
    if (v >= V_N) continue;
    float r  = sigf(ar[n] + br[n] + b_r);
    float z  = sigf(az[n] + bz[n] + b_z);
    float nn = tanhf(an[n] + bin + r*(bn2[n] + bhn));
    h[(size_t)v*64 + o] = (1.f - z)*nn + z*hv[n];
    aggz[(size_t)v*64 + o] = 0.f;              // re-zero for next msg step
  }
}

// ---------------- graph segment starts via binary search (node2graph is sorted)
__global__ void gstart_kernel(const int* n2g, int* gstart) {
  int g = blockIdx.x * 256 + threadIdx.x;
  if (g > G_N) return;
  int lo = 0, hi = V_N;
  while (lo < hi) { int mid = (lo + hi) >> 1; if (n2g[mid] < g) lo = mid + 1; else hi = mid; }
  gstart[g] = lo;
}

// ---------------- fused Set2Set v3: 4 graphs per 256-thread block; LSTM weights as bf16 uint4 quads
__global__ __launch_bounds__(256) void s2s_kernel(const float* h, const int* gstart,
    const uint4* TW40, const uint4* TU40, const uint4* TW4r, const uint4* TU4r,
    const float* bih0, const float* bhh0, const float* bihr, const float* bhhr,
    float* qstar) {
  __shared__ float sq[4][128];
  __shared__ float sx[4][128];
  __shared__ float shs[4][3][64], scs[4][3][64];
  __shared__ float sg[4][256];
  int tt = threadIdx.x;
  int g0blk = blockIdx.x * 4;
  int w = tt >> 6, lane = tt & 63;
  int nstart = gstart[g0blk + w], nend = gstart[g0blk + w + 1];

  for (int i = tt; i < 512; i += 256) ((float*)sq)[i] = 0.f;
  for (int i = tt; i < 768; i += 256) { ((float*)shs)[i] = 0.f; ((float*)scs)[i] = 0.f; }
  __syncthreads();

  for (int iter = 0; iter < NS2S; ++iter) {
    for (int i = tt; i < 512; i += 256) ((float*)sx)[i] = ((float*)sq)[i];
    __syncthreads();

    for (int l = 0; l < 3; ++l) {
      const uint4* TW = (l == 0) ? TW40 : TW4r + (size_t)(l-1) * 2048;
      const uint4* TU = (l == 0) ? TU40 : TU4r + (size_t)(l-1) * 2048;
      const float* bi = (l == 0) ? bih0 : bihr + (l-1)*256;
      const float* bh = (l == 0) ? bhh0 : bhhr + (l-1)*256;
      float bsum = bi[tt] + bh[tt];
      float acc[4] = {bsum, bsum, bsum, bsum};
      if (l == 0) {
        #pragma unroll
        for (int k8 = 0; k8 < 16; ++k8) {
          uint4 u = TW[k8*256 + tt];
          #pragma unroll
          for (int gi = 0; gi < 4; ++gi) {
            const float4 xa = *(const float4*)&sx[gi][k8*8];
            const float4 xb = *(const float4*)&sx[gi][k8*8 + 4];
            acc[gi] += xa.x*bflo(u.x) + xa.y*bfhi(u.x) + xa.z*bflo(u.y) + xa.w*bfhi(u.y)
                     + xb.x*bflo(u.z) + xb.y*bfhi(u.z) + xb.z*bflo(u.w) + xb.w*bfhi(u.w);
          }
        }
      } else {
        #pragma unroll
        for (int k8 = 0; k8 < 8; ++k8) {
          uint4 u = TW[k8*256 + tt];
          #pragma unroll
          for (int gi = 0; gi < 4; ++gi) {
            const float4 xa = *(const float4*)&sx[gi][k8*8];
            const float4 xb = *(const float4*)&sx[gi][k8*8 + 4];
            acc[gi] += xa.x*bflo(u.x) + xa.y*bfhi(u.x) + xa.z*bflo(u.y) + xa.w*bfhi(u.y)
                     + xb.x*bflo(u.z) + xb.y*bfhi(u.z) + xb.z*bflo(u.w) + xb.w*bfhi(u.w);
          }
        }
      }
      #pragma unroll
      for (int k8 = 0; k8 < 8; ++k8) {
        uint4 u = TU[k8*256 + tt];
        #pragma unroll
        for (int gi = 0; gi < 4; ++gi) {
          const float4 ha = *(const float4*)&shs[gi][l][k8*8];
          const float4 hb = *(const float4*)&shs[gi][l][k8*8 + 4];
          acc[gi] += ha.x*bflo(u.x) + ha.y*bfhi(u.x) + ha.z*bflo(u.y) + ha.w*bfhi(u.y)
                   + hb.x*bflo(u.z) + hb.y*bfhi(u.z) + hb.z*bflo(u.w) + hb.w*bfhi(u.w);
        }
      }
      #pragma unroll
      for (int gi = 0; gi < 4; ++gi) sg[gi][tt] = acc[gi];
      __syncthreads();
      {
        int gq = tt >> 6, r = tt & 63;
        float gv_i = sg[gq][r], gv_f = sg[gq][64+r], gv_g = sg[gq][128+r], gv_o = sg[gq][192+r];
        float c = sigf(gv_f)*scs[gq][l][r] + sigf(gv_i)*tanhf(gv_g);
        float hc = sigf(gv_o)*tanhf(c);
        scs[gq][l][r] = c; shs[gq][l][r] = hc; sx[gq][r] = hc;
      }
      __syncthreads();
    }

    // attention: wave w owns graph g0blk+w; q = sx[w][0:64]
    {
      float q_l = sx[w][lane];
      float lmax = -3.4e38f;
      int i = nstart;
      for (; i + 1 < nend; i += 2) {
        float h0 = h[(size_t)i*64 + lane];
        float h1 = h[(size_t)(i+1)*64 + lane];
        float v0 = h0 * q_l, v1 = h1 * q_l;
        #pragma unroll
        for (int off = 32; off; off >>= 1) { v0 += __shfl_xor(v0, off); v1 += __shfl_xor(v1, off); }
        lmax = fmaxf(lmax, fmaxf(v0, v1));
      }
      if (i < nend) {
        float h0 = h[(size_t)i*64 + lane];
        float v0 = h0 * q_l;
        #pragma unroll
        for (int off = 32; off; off >>= 1) v0 += __shfl_xor(v0, off);
        lmax = fmaxf(lmax, v0);
      }
      float lsum = 0.f, accv = 0.f;
      i = nstart;
      for (; i + 1 < nend; i += 2) {
        float h0 = h[(size_t)i*64 + lane];
        float h1 = h[(size_t)(i+1)*64 + lane];
        float v0 = h0 * q_l, v1 = h1 * q_l;
        #pragma unroll
        for (int off = 32; off; off >>= 1) { v0 += __shfl_xor(v0, off); v1 += __shfl_xor(v1, off); }
        float e0 = expf(v0 - lmax), e1 = expf(v1 - lmax);
        lsum += e0 + e1; accv += e0*h0 + e1*h1;
      }
      if (i < nend) {
        float h0 = h[(size_t)i*64 + lane];
        float v0 = h0 * q_l;
        #pragma unroll
        for (int off = 32; off; off >>= 1) v0 += __shfl_xor(v0, off);
        float e0 = expf(v0 - lmax);
        lsum += e0; accv += e0*h0;
      }
      sq[w][lane] = sx[w][lane];
      sq[w][64 + lane] = accv / fmaxf(lsum, 1e-12f);
    }
    __syncthreads();
  }

  for (int i = tt; i < 512; i += 256) qstar[(size_t)g0blk * 128 + i] = ((float*)sq)[i];
}

// ---------------- head: Linear+ReLU+BN(eval)+Linear + evidential transform; wave per graph
__global__ void head_kernel(const float* qstar, const float* W1, const float* b1,
                            const float* gma, const float* gbe, const float* gme, const float* gva,
                            const float* W2, const float* b2, float* out) {
  __shared__ float hb[4][64];
  int wslot = threadIdx.x >> 6;
  int g = blockIdx.x * 4 + wslot;
  int o = threadIdx.x & 63;
  float acc = b1[o];
  const float* q = qstar + (size_t)g * 128;
  #pragma unroll 4
  for (int k = 0; k < 128; ++k) acc += q[k] * W1[k*64 + o];
  acc = fmaxf(acc, 0.f);
  float hbn = gma[o] * (acc - gme[o]) * rsqrtf(gva[o] + 1e-5f) + gbe[o];
  hb[wslot][o] = hbn;
  __syncthreads();
  if (o < 4) {
    float v = b2[o];
    #pragma unroll 8
    for (int k = 0; k < 64; ++k) v += hb[wslot][k] * W2[k*4 + o];
    float res;
    if (o == 0) res = v;
    else { res = splusf(v) + 1e-6f; if (o == 2) res += 1.f; }
    out[(size_t)g*4 + o] = res;
  }
}

extern "C" void kernel_launch(void* const* d_in, const int* in_sizes, int n_in,
                              void* d_out, int out_size, void* d_ws, size_t ws_size,
                              hipStream_t stream) {
  const float* node_feats = (const float*)d_in[0];
  const float* edge_feats = (const float*)d_in[1];
  const int*   src        = (const int*)d_in[2];
  const int*   dst        = (const int*)d_in[3];
  const int*   n2g        = (const int*)d_in[4];
  const float* W_proj = (const float*)d_in[5];
  const float* b_proj = (const float*)d_in[6];
  const float* W_e1   = (const float*)d_in[7];
  const float* b_e1   = (const float*)d_in[8];
  const float* W_e2   = (const float*)d_in[9];
  const float* b_e2   = (const float*)d_in[10];
  const float* b_conv = (const float*)d_in[11];
  const float* gru_W_ih = (const float*)d_in[12];
  const float* gru_W_hh = (const float*)d_in[13];
  const float* gru_b_ih = (const float*)d_in[14];
  const float* gru_b_hh = (const float*)d_in[15];
  const float* lstm_W_ih0 = (const float*)d_in[16];
  const float* lstm_W_hh0 = (const float*)d_in[17];
  const float* lstm_b_ih0 = (const float*)d_in[18];
  const float* lstm_b_hh0 = (const float*)d_in[19];
  const float* lstm_W_ih_r = (const float*)d_in[20];
  const float* lstm_W_hh_r = (const float*)d_in[21];
  const float* lstm_b_ih_r = (const float*)d_in[22];
  const float* lstm_b_hh_r = (const float*)d_in[23];
  const float* W1 = (const float*)d_in[24];
  const float* b1 = (const float*)d_in[25];
  const float* bn_gamma = (const float*)d_in[26];
  const float* bn_beta  = (const float*)d_in[27];
  const float* bn_mean  = (const float*)d_in[28];
  const float* bn_var   = (const float*)d_in[29];
  const float* W2 = (const float*)d_in[30];
  const float* b2 = (const float*)d_in[31];

  char* ws = (char*)d_ws;
  size_t off = 0;
  auto alloc = [&](size_t n) { size_t c = off; off += (n + 255) & ~(size_t)255; return c; };
  u16*   zb     = (u16*)  (ws + alloc((size_t)MPAD * 128 * 2));   // 12.8 MB
  float* h      = (float*)(ws + alloc((size_t)V_N * 64 * 4));     //  6.4 MB
  float* agg    = (float*)(ws + alloc((size_t)V_N * 64 * 4));     //  6.4 MB
  u16*   WbT    = (u16*)  (ws + alloc((size_t)4096 * 128 * 2));   //  1.0 MB
  float* gWihT  = (float*)(ws + alloc(12288 * 4));
  float* gWhhT  = (float*)(ws + alloc(12288 * 4));
  u32*   TW40   = (u32*)  (ws + alloc(16384 * 4));
  u32*   TU40   = (u32*)  (ws + alloc(8192 * 4));
  u32*   TW4r   = (u32*)  (ws + alloc(16384 * 4));
  u32*   TU4r   = (u32*)  (ws + alloc(16384 * 4));
  int*   gstart = (int*)  (ws + alloc(1025 * 4));
  float* qstar  = (float*)(ws + alloc((size_t)G_N * 128 * 4));
  (void)in_sizes; (void)n_in; (void)out_size; (void)ws_size;

  prep_kernel<<<2368, 256, 0, stream>>>(gru_W_ih, gru_W_hh, lstm_W_ih0, lstm_W_hh0,
                                        lstm_W_ih_r, lstm_W_hh_r, W_e2,
                                        gWihT, gWhhT, TW40, TU40, TW4r, TU4r, WbT);
  proj_kernel<<<6250, 256, 0, stream>>>(node_feats, W_proj, b_proj, h);
  edgenet_kernel<<<MPAD / 2, 256, 0, stream>>>(edge_feats, W_e1, b_e1, zb);
  hipMemsetAsync(agg, 0, (size_t)V_N * 64 * 4, stream);

  for (int st = 0; st < NSTEPS; ++st) {
    fusedmsg_kernel<<<MPAD / 128, 512, 0, stream>>>(zb, WbT, b_e2, h, src, dst, agg);
    gru_kernel<<<1563, 256, 0, stream>>>(agg, b_conv, gWihT, gWhhT, gru_b_ih, gru_b_hh, h, agg);
  }

  gstart_kernel<<<5, 256, 0, stream>>>(n2g, gstart);
  s2s_kernel<<<256, 256, 0, stream>>>(h, gstart, (const uint4*)TW40, (const uint4*)TU40,
                                      (const uint4*)TW4r, (const uint4*)TU4r,
                                      lstm_b_ih0, lstm_b_hh0, lstm_b_ih_r, lstm_b_hh_r, qstar);
  head_kernel<<<256, 256, 0, stream>>>(qstar, W1, b1, bn_gamma, bn_beta, bn_mean, bn_var,
                                       W2, b2, (float*)d_out);
}